// Round 1
// baseline (10970.235 us; speedup 1.0000x reference)
//
#include <hip/hip_runtime.h>
#include <cstddef>

#define BB 32
#define PP 196
#define ENCD 2048
#define EMBD 512
#define DECD 512
#define ATTD 512
#define VV 10000
#define LLEN 52
#define TT 51
#define NKC 10  // k-chunks in k_gstep (2560 / 256)

// output offsets (floats)
#define OFF_PRED  0
#define OFF_TOKS  16320000
#define OFF_DLEN  16321664
#define OFF_ALPHA 16321696
#define OFF_SIDX  16641568

__device__ __forceinline__ float sigmf(float x) { return 1.0f / (1.0f + __expf(-x)); }

// ---------------------------------------------------------------- sort
__global__ void k_sort(const int* __restrict__ toks, const int* __restrict__ lens,
                       int* __restrict__ sidx, int* __restrict__ dlen, float* __restrict__ out) {
    __shared__ int s_idx[BB];
    if (threadIdx.x == 0) {
        int idx[BB], ln[BB];
        for (int i = 0; i < BB; i++) { idx[i] = i; ln[i] = lens[i]; }
        // stable insertion sort, descending by length (ties keep original order)
        for (int i = 1; i < BB; i++) {
            int ci = idx[i], cl = ln[i]; int j = i - 1;
            while (j >= 0 && ln[j] < cl) { ln[j + 1] = ln[j]; idx[j + 1] = idx[j]; j--; }
            ln[j + 1] = cl; idx[j + 1] = ci;
        }
        for (int i = 0; i < BB; i++) {
            s_idx[i] = idx[i];
            sidx[i] = idx[i];
            int d = ln[i] - 1;
            dlen[i] = d;
            out[OFF_DLEN + i] = (float)d;
            out[OFF_SIDX + i] = (float)idx[i];
        }
    }
    __syncthreads();
    for (int i = threadIdx.x; i < BB * LLEN; i += blockDim.x) {
        int b = i / LLEN, l = i % LLEN;
        out[OFF_TOKS + i] = (float)toks[s_idx[b] * LLEN + l];
    }
}

// ---------------------------------------------------------------- mean + h0/c0
__global__ void k_init(const float* __restrict__ img, const int* __restrict__ sidx,
                       const float* __restrict__ Wh0, const float* __restrict__ bh0,
                       const float* __restrict__ Wc0, const float* __restrict__ bc0,
                       float* __restrict__ h, float* __restrict__ c) {
    int b = blockIdx.x;
    int sb = sidx[b];
    __shared__ float smean[ENCD];
    const float* ib = img + (size_t)sb * PP * ENCD;
    for (int e = threadIdx.x; e < ENCD; e += 256) {
        float acc = 0.f;
        for (int p = 0; p < PP; p++) acc += ib[(size_t)p * ENCD + e];
        smean[e] = acc * (1.0f / 196.0f);
    }
    __syncthreads();
    for (int d = threadIdx.x; d < DECD; d += 256) {
        const float* wh = Wh0 + (size_t)d * ENCD;
        const float* wc = Wc0 + (size_t)d * ENCD;
        float ah = bh0[d], ac = bc0[d];
        for (int e = 0; e < ENCD; e++) { float m = smean[e]; ah += m * wh[e]; ac += m * wc[e]; }
        h[b * DECD + d] = ah;
        c[b * DECD + d] = ac;
    }
}

// ---------------------------------------------------------------- enc_att = img @ W_enc^T + b_enc
// M = 6272 rows (sorted b, p), N = 512, K = 2048. grid (196, 8), block 256.
__global__ void k_enc(const float* __restrict__ img, const int* __restrict__ sidx,
                      const float* __restrict__ Wenc, const float* __restrict__ benc,
                      float* __restrict__ enc_att) {
    __shared__ float As[32][33];
    __shared__ float Ws[32][65];
    __shared__ size_t rb[32];
    int row0 = blockIdx.x * 32, col0 = blockIdx.y * 64;
    int tid = threadIdx.x;
    int tr = tid & 31, tc = tid >> 5;
    if (tid < 32) {
        int row = row0 + tid;
        int b = row / PP, p = row % PP;
        rb[tid] = ((size_t)sidx[b] * PP + p) * ENCD;
    }
    __syncthreads();
    float acc[8] = {0, 0, 0, 0, 0, 0, 0, 0};
    for (int kk = 0; kk < ENCD; kk += 32) {
        for (int i = tid; i < 1024; i += 256) {
            int r = i >> 5, k = i & 31;
            As[r][k] = img[rb[r] + kk + k];
        }
        for (int i = tid; i < 2048; i += 256) {
            int cc = i >> 5, k = i & 31;
            Ws[k][cc] = Wenc[(size_t)(col0 + cc) * ENCD + kk + k];
        }
        __syncthreads();
        for (int k = 0; k < 32; k++) {
            float a = As[tr][k];
#pragma unroll
            for (int j = 0; j < 8; j++) acc[j] += a * Ws[k][tc * 8 + j];
        }
        __syncthreads();
    }
    int row = row0 + tr;
    float* crow = enc_att + (size_t)row * ATTD + col0 + tc * 8;
#pragma unroll
    for (int j = 0; j < 8; j++) crow[j] = acc[j] + benc[col0 + tc * 8 + j];
}

// ---------------------------------------------------------------- g_base = emb_t @ W_ih[:, :512]^T + b_ih + b_hh
// rows = t*32 + b (t = blockIdx.x), N = 2048, K = 512. grid (51, 32), block 256.
__global__ void k_gemb(const float* __restrict__ emb, const int* __restrict__ toks,
                       const int* __restrict__ sidx, const float* __restrict__ Wih,
                       const float* __restrict__ bih, const float* __restrict__ bhh,
                       float* __restrict__ gbase) {
    __shared__ float As[32][33];
    __shared__ float Ws[32][65];
    __shared__ size_t rb[32];
    int row0 = blockIdx.x * 32, col0 = blockIdx.y * 64;
    int tid = threadIdx.x;
    int tr = tid & 31, tc = tid >> 5;
    if (tid < 32) {
        int t = blockIdx.x, b = tid;
        int tok = toks[sidx[b] * LLEN + t];
        rb[tid] = (size_t)tok * EMBD;
    }
    __syncthreads();
    float acc[8] = {0, 0, 0, 0, 0, 0, 0, 0};
    for (int kk = 0; kk < EMBD; kk += 32) {
        for (int i = tid; i < 1024; i += 256) {
            int r = i >> 5, k = i & 31;
            As[r][k] = emb[rb[r] + kk + k];
        }
        for (int i = tid; i < 2048; i += 256) {
            int cc = i >> 5, k = i & 31;
            Ws[k][cc] = Wih[(size_t)(col0 + cc) * (EMBD + ENCD) + kk + k];
        }
        __syncthreads();
        for (int k = 0; k < 32; k++) {
            float a = As[tr][k];
#pragma unroll
            for (int j = 0; j < 8; j++) acc[j] += a * Ws[k][tc * 8 + j];
        }
        __syncthreads();
    }
    int row = row0 + tr;
    float* crow = gbase + (size_t)row * 2048 + col0 + tc * 8;
#pragma unroll
    for (int j = 0; j < 8; j++) {
        int col = col0 + tc * 8 + j;
        crow[j] = acc[j] + bih[col] + bhh[col];
    }
}

// ---------------------------------------------------------------- per-step attention (blocks 0..31) + beta gate (blocks 32..63)
__global__ void k_attn(int t, const float* __restrict__ img, const int* __restrict__ sidx,
                       const int* __restrict__ dlen, const float* __restrict__ Wdec,
                       const float* __restrict__ bdec, const float* __restrict__ wfull,
                       const float* __restrict__ enc_att, const float* __restrict__ Wbeta,
                       const float* __restrict__ bbeta, const float* __restrict__ h,
                       float* __restrict__ awe, float* __restrict__ gate,
                       float* __restrict__ alpha_out) {
    __shared__ float smem[BB * DECD];  // 64 KiB; gate path uses all, attn path carves pieces
    int tid = threadIdx.x;
    if (blockIdx.x < 32) {
        float* sh = smem;            // 512
        float* sw = smem + 512;      // 512
        float* sdec = smem + 1024;   // 512
        float* sal = smem + 1536;    // 256 (196 used)
        float* sred = smem + 1792;   // 256
        int b = blockIdx.x;
        for (int i = tid; i < 512; i += 256) { sh[i] = h[b * DECD + i]; sw[i] = wfull[i]; }
        __syncthreads();
        // dec_att
        for (int a = tid; a < ATTD; a += 256) {
            const float* wr = Wdec + (size_t)a * DECD;
            float acc = bdec[a];
            for (int k = 0; k < DECD; k++) acc += sh[k] * wr[k];
            sdec[a] = acc;
        }
        __syncthreads();
        // scores: one wave per p
        int wv = tid >> 6, ln = tid & 63;
        const float* eb = enc_att + (size_t)b * PP * ATTD;
        for (int p = wv; p < PP; p += 4) {
            const float* er = eb + (size_t)p * ATTD;
            float acc = 0.f;
            for (int a = ln; a < ATTD; a += 64) {
                float v = er[a] + sdec[a];
                acc += (v > 0.f ? v : 0.f) * sw[a];
            }
            for (int off = 32; off; off >>= 1) acc += __shfl_down(acc, off);
            if (ln == 0) sal[p] = acc;
        }
        __syncthreads();
        // softmax over 196
        float v = (tid < PP) ? sal[tid] : -1e30f;
        sred[tid] = v;
        __syncthreads();
        for (int s = 128; s; s >>= 1) { if (tid < s) sred[tid] = fmaxf(sred[tid], sred[tid + s]); __syncthreads(); }
        float mx = sred[0];
        __syncthreads();
        float e = (tid < PP) ? __expf(v - mx) : 0.f;
        sred[tid] = e;
        __syncthreads();
        for (int s = 128; s; s >>= 1) { if (tid < s) sred[tid] += sred[tid + s]; __syncthreads(); }
        float inv = 1.f / sred[0];
        bool active = t < dlen[b];
        float al = e * inv;
        if (tid < PP) {
            sal[tid] = al;
            alpha_out[((size_t)b * TT + t) * PP + tid] = active ? al : 0.f;
        }
        __syncthreads();
        // awe = alpha @ img
        const float* ib = img + (size_t)sidx[b] * PP * ENCD;
        for (int ee = tid; ee < ENCD; ee += 256) {
            float acc = 0.f;
            for (int p = 0; p < PP; p++) acc += sal[p] * ib[(size_t)p * ENCD + ee];
            awe[b * ENCD + ee] = acc;
        }
    } else {
        // gate = sigmoid(h @ W_beta^T + b_beta), weight-stationary over batch
        float* shAll = smem;  // 32 x 512
        int g = blockIdx.x - 32;
        for (int i = tid; i < BB * DECD; i += 256) shAll[i] = h[i];
        __syncthreads();
        int el = tid & 63, bg = tid >> 6;  // bg in 0..3 -> 8 batch rows each
        int e = g * 64 + el;
        const float* wr = Wbeta + (size_t)e * DECD;
        float acc[8] = {0, 0, 0, 0, 0, 0, 0, 0};
        for (int k = 0; k < DECD; k++) {
            float w = wr[k];
#pragma unroll
            for (int j = 0; j < 8; j++) acc[j] += w * shAll[(bg * 8 + j) * DECD + k];
        }
        float bb = bbeta[e];
#pragma unroll
        for (int j = 0; j < 8; j++) gate[(bg * 8 + j) * ENCD + e] = sigmf(acc[j] + bb);
    }
}

// ---------------------------------------------------------------- g partials: [awe_gated ; h] @ [W_ih[:,512:] ; W_hh]^T
// grid (8 d-chunks, 10 k-chunks), block 256; one output-d per thread, 32 batch accumulators.
__global__ void k_gstep(const float* __restrict__ awe, const float* __restrict__ gate,
                        const float* __restrict__ h, const float* __restrict__ Wih,
                        const float* __restrict__ Whh, float* __restrict__ gpart) {
    __shared__ float sx[BB][257];
    int dc = blockIdx.x, kc = blockIdx.y, tid = threadIdx.x;
    int k0 = kc * 256;
    for (int i = tid; i < BB * 256; i += 256) {
        int b = i >> 8, k = i & 255;
        int kg = k0 + k;
        float v;
        if (kg < ENCD) v = awe[b * ENCD + kg] * gate[b * ENCD + kg];
        else v = h[b * DECD + (kg - ENCD)];
        sx[b][k] = v;
    }
    __syncthreads();
    int d = dc * 256 + tid;
    float acc[BB];
#pragma unroll
    for (int b = 0; b < BB; b++) acc[b] = 0.f;
    const float* wr;
    if (k0 < ENCD) wr = Wih + (size_t)d * (EMBD + ENCD) + EMBD + k0;
    else wr = Whh + (size_t)d * DECD + (k0 - ENCD);
    for (int k = 0; k < 256; k++) {
        float w = wr[k];
#pragma unroll
        for (int b = 0; b < BB; b++) acc[b] += w * sx[b][k];
    }
    for (int b = 0; b < BB; b++) gpart[((size_t)kc * BB + b) * 2048 + d] = acc[b];
}

// ---------------------------------------------------------------- reduce partials, LSTM cell update, mask, record h
__global__ void k_update(int t, const float* __restrict__ gbase, const float* __restrict__ gpart,
                         const int* __restrict__ dlen, float* __restrict__ h, float* __restrict__ c,
                         float* __restrict__ h_hist) {
    int b = blockIdx.x, tid = threadIdx.x;
    bool active = t < dlen[b];
    const float* gb = gbase + ((size_t)t * BB + b) * 2048;
    for (int d = tid; d < DECD; d += 256) {
        float gi = gb[d], gf = gb[d + 512], gg = gb[d + 1024], go = gb[d + 1536];
        for (int kc = 0; kc < NKC; kc++) {
            const float* gp = gpart + ((size_t)kc * BB + b) * 2048;
            gi += gp[d]; gf += gp[d + 512]; gg += gp[d + 1024]; go += gp[d + 1536];
        }
        float i_ = sigmf(gi), f_ = sigmf(gf), g_ = tanhf(gg), o_ = sigmf(go);
        float cn = f_ * c[b * DECD + d] + i_ * g_;
        float hn = o_ * tanhf(cn);
        float hv;
        if (active) { c[b * DECD + d] = cn; h[b * DECD + d] = hn; hv = hn; }
        else hv = h[b * DECD + d];
        h_hist[((size_t)t * BB + b) * DECD + d] = hv;
    }
}

// ---------------------------------------------------------------- predictions = h_hist @ W_fc^T + b_fc (masked)
// M = 1632 (t*32+b), N = 10000, K = 512. grid (51, 157), block 256.
__global__ void k_pred(const float* __restrict__ h_hist, const float* __restrict__ Wfc,
                       const float* __restrict__ bfc, const int* __restrict__ dlen,
                       float* __restrict__ out) {
    __shared__ float As[32][33];
    __shared__ float Ws[32][65];
    int row0 = blockIdx.x * 32, col0 = blockIdx.y * 64;
    int tid = threadIdx.x;
    int tr = tid & 31, tc = tid >> 5;
    float acc[8] = {0, 0, 0, 0, 0, 0, 0, 0};
    for (int kk = 0; kk < DECD; kk += 32) {
        for (int i = tid; i < 1024; i += 256) {
            int r = i >> 5, k = i & 31;
            As[r][k] = h_hist[(size_t)(row0 + r) * DECD + kk + k];
        }
        for (int i = tid; i < 2048; i += 256) {
            int cc = i >> 5, k = i & 31;
            int col = col0 + cc;
            Ws[k][cc] = (col < VV) ? Wfc[(size_t)col * DECD + kk + k] : 0.f;
        }
        __syncthreads();
        for (int k = 0; k < 32; k++) {
            float a = As[tr][k];
#pragma unroll
            for (int j = 0; j < 8; j++) acc[j] += a * Ws[k][tc * 8 + j];
        }
        __syncthreads();
    }
    int row = row0 + tr;
    int t = row >> 5, b = row & 31;
    bool active = t < dlen[b];
    float* orow = out + OFF_PRED + ((size_t)b * TT + t) * VV;
#pragma unroll
    for (int j = 0; j < 8; j++) {
        int col = col0 + tc * 8 + j;
        if (col < VV) orow[col] = active ? (acc[j] + bfc[col]) : 0.f;
    }
}

// ---------------------------------------------------------------- launch
extern "C" void kernel_launch(void* const* d_in, const int* in_sizes, int n_in,
                              void* d_out, int out_size, void* d_ws, size_t ws_size,
                              hipStream_t stream) {
    const float* img   = (const float*)d_in[0];
    const int*   toks  = (const int*)d_in[1];
    const int*   lens  = (const int*)d_in[2];
    const float* Wenc  = (const float*)d_in[3];
    const float* benc  = (const float*)d_in[4];
    const float* Wdec  = (const float*)d_in[5];
    const float* bdec  = (const float*)d_in[6];
    const float* wfull = (const float*)d_in[7];
    // d_in[8] = b_full (scalar 0; softmax-invariant, unused)
    const float* emb   = (const float*)d_in[9];
    const float* Wih   = (const float*)d_in[10];
    const float* bih   = (const float*)d_in[11];
    const float* Whh   = (const float*)d_in[12];
    const float* bhh   = (const float*)d_in[13];
    const float* Wh0   = (const float*)d_in[14];
    const float* bh0   = (const float*)d_in[15];
    const float* Wc0   = (const float*)d_in[16];
    const float* bc0   = (const float*)d_in[17];
    const float* Wbeta = (const float*)d_in[18];
    const float* bbeta = (const float*)d_in[19];
    const float* Wfc   = (const float*)d_in[20];
    const float* bfc   = (const float*)d_in[21];
    float* out = (float*)d_out;

    // workspace layout
    char* ws = (char*)d_ws;
    int* sidx = (int*)ws;                 ws += 256;                       // 32 ints (+pad)
    int* dlen = (int*)ws;                 ws += 256;
    float* h       = (float*)ws;          ws += (size_t)BB * DECD * 4;
    float* c       = (float*)ws;          ws += (size_t)BB * DECD * 4;
    float* awe     = (float*)ws;          ws += (size_t)BB * ENCD * 4;
    float* gate    = (float*)ws;          ws += (size_t)BB * ENCD * 4;
    float* gpart   = (float*)ws;          ws += (size_t)NKC * BB * 2048 * 4;
    float* h_hist  = (float*)ws;          ws += (size_t)TT * BB * DECD * 4;
    float* enc_att = (float*)ws;          ws += (size_t)BB * PP * ATTD * 4;
    float* gbase   = (float*)ws;          ws += (size_t)TT * BB * 2048 * 4;

    k_sort<<<1, 64, 0, stream>>>(toks, lens, sidx, dlen, out);
    k_init<<<32, 256, 0, stream>>>(img, sidx, Wh0, bh0, Wc0, bc0, h, c);
    k_enc<<<dim3(196, 8), 256, 0, stream>>>(img, sidx, Wenc, benc, enc_att);
    k_gemb<<<dim3(51, 32), 256, 0, stream>>>(emb, toks, sidx, Wih, bih, bhh, gbase);

    for (int t = 0; t < TT; t++) {
        k_attn<<<64, 256, 0, stream>>>(t, img, sidx, dlen, Wdec, bdec, wfull,
                                       enc_att, Wbeta, bbeta, h, awe, gate, out + OFF_ALPHA);
        k_gstep<<<dim3(8, NKC), 256, 0, stream>>>(awe, gate, h, Wih, Whh, gpart);
        k_update<<<32, 256, 0, stream>>>(t, gbase, gpart, dlen, h, c, h_hist);
    }

    k_pred<<<dim3(51, 157), 256, 0, stream>>>(h_hist, Wfc, bfc, dlen, out);
}

// Round 3
// 6446.149 us; speedup vs baseline: 1.7018x; 1.7018x over previous
//
#include <hip/hip_runtime.h>
#include <hip/hip_bf16.h>
#include <cstddef>

#define BB 32
#define PP 196
#define ENCD 2048
#define EMBD 512
#define DECD 512
#define ATTD 512
#define VV 10000
#define LLEN 52
#define TT 51
#define GKC 8    // k-chunks in k_gstep (2560/320)

// output offsets (floats)
#define OFF_PRED  0
#define OFF_TOKS  16320000
#define OFF_DLEN  16321664
#define OFF_ALPHA 16321696
#define OFF_SIDX  16641568

typedef __attribute__((ext_vector_type(8))) short short8;
typedef __attribute__((ext_vector_type(4))) float floatx4;

__device__ __forceinline__ float sigmf(float x) { return 1.0f / (1.0f + __expf(-x)); }
__device__ __forceinline__ unsigned short f2bf(float x) {
    __hip_bfloat16 h = __float2bfloat16(x);
    return *(unsigned short*)&h;
}

// ---------------------------------------------------------------- sort
__global__ void k_sort(const int* __restrict__ toks, const int* __restrict__ lens,
                       int* __restrict__ sidx, int* __restrict__ dlen, float* __restrict__ out) {
    __shared__ int s_idx[BB];
    if (threadIdx.x == 0) {
        int idx[BB], ln[BB];
        for (int i = 0; i < BB; i++) { idx[i] = i; ln[i] = lens[i]; }
        for (int i = 1; i < BB; i++) {           // stable insertion sort, descending
            int ci = idx[i], cl = ln[i]; int j = i - 1;
            while (j >= 0 && ln[j] < cl) { ln[j + 1] = ln[j]; idx[j + 1] = idx[j]; j--; }
            ln[j + 1] = cl; idx[j + 1] = ci;
        }
        for (int i = 0; i < BB; i++) {
            s_idx[i] = idx[i];
            sidx[i] = idx[i];
            int d = ln[i] - 1;
            dlen[i] = d;
            out[OFF_DLEN + i] = (float)d;
            out[OFF_SIDX + i] = (float)idx[i];
        }
    }
    __syncthreads();
    for (int i = threadIdx.x; i < BB * LLEN; i += blockDim.x) {
        int b = i / LLEN, l = i % LLEN;
        out[OFF_TOKS + i] = (float)toks[s_idx[b] * LLEN + l];
    }
}

// ---------------------------------------------------------------- mean + h0/c0 (h -> xT tail, transposed)
__global__ void k_init(const float* __restrict__ img, const int* __restrict__ sidx,
                       const float* __restrict__ Wh0, const float* __restrict__ bh0,
                       const float* __restrict__ Wc0, const float* __restrict__ bc0,
                       float* __restrict__ xT, float* __restrict__ c) {
    int b = blockIdx.x;
    int sb = sidx[b];
    __shared__ float smean[ENCD];
    const float* ib = img + (size_t)sb * PP * ENCD;
    for (int e = threadIdx.x; e < ENCD; e += 256) {
        float acc = 0.f;
        for (int p = 0; p < PP; p++) acc += ib[(size_t)p * ENCD + e];
        smean[e] = acc * (1.0f / 196.0f);
    }
    __syncthreads();
    for (int d = threadIdx.x; d < DECD; d += 256) {
        const float* wh = Wh0 + (size_t)d * ENCD;
        const float* wc = Wc0 + (size_t)d * ENCD;
        float ah = bh0[d], ac = bc0[d];
        for (int e = 0; e < ENCD; e++) { float m = smean[e]; ah += m * wh[e]; ac += m * wc[e]; }
        xT[(2048 + d) * BB + b] = ah;     // hT
        c[b * DECD + d] = ac;
    }
}

// ---------------------------------------------------------------- transpose loop weights (k-major)
// WgT[k][d] = k<2048 ? Wih[d][512+k] : Whh[d][k-2048];  k<2560, d<2048
__global__ void k_twg(const float* __restrict__ Wih, const float* __restrict__ Whh,
                      float* __restrict__ WgT) {
    __shared__ float sT[32][33];
    int kt = blockIdx.x, dt = blockIdx.y;
    int tx = threadIdx.x & 31, ty = threadIdx.x >> 5;  // ty 0..7
    for (int j = 0; j < 4; j++) {
        int dd = dt * 32 + ty + j * 8;
        int kk = kt * 32 + tx;
        float v = (kk < 2048) ? Wih[(size_t)dd * 2560 + 512 + kk]
                              : Whh[(size_t)dd * 512 + (kk - 2048)];
        sT[ty + j * 8][tx] = v;
    }
    __syncthreads();
    for (int j = 0; j < 4; j++) {
        int kk = kt * 32 + ty + j * 8;
        int dd = dt * 32 + tx;
        WgT[(size_t)kk * 2048 + dd] = sT[tx][ty + j * 8];
    }
}

// WhT[k][col] = col<512 ? Wdec[col][k] : Wbeta[col-512][k];  k<512, col<2560
__global__ void k_twh(const float* __restrict__ Wdec, const float* __restrict__ Wbeta,
                      float* __restrict__ WhT) {
    __shared__ float sT[32][33];
    int kt = blockIdx.x, ct = blockIdx.y;
    int tx = threadIdx.x & 31, ty = threadIdx.x >> 5;
    for (int j = 0; j < 4; j++) {
        int cc = ct * 32 + ty + j * 8;
        int kk = kt * 32 + tx;
        float v = (cc < 512) ? Wdec[(size_t)cc * 512 + kk]
                             : Wbeta[(size_t)(cc - 512) * 512 + kk];
        sT[ty + j * 8][tx] = v;
    }
    __syncthreads();
    for (int j = 0; j < 4; j++) {
        int kk = kt * 32 + ty + j * 8;
        int cc = ct * 32 + tx;
        WhT[(size_t)kk * 2560 + cc] = sT[tx][ty + j * 8];
    }
}

// WfcB: bf16 convert of Wfc [10000][512], layout unchanged
__global__ void k_cvtfc(const float* __restrict__ Wfc, unsigned int* __restrict__ WfcB) {
    int base = (blockIdx.x * 256 + threadIdx.x) * 4;
    for (int j = 0; j < 4; j++) {
        int ui = base + j;                 // 0 .. 2,560,000
        const float* src = Wfc + (size_t)ui * 2;
        unsigned int lo = f2bf(src[0]), hi = f2bf(src[1]);
        WfcB[ui] = lo | (hi << 16);
    }
}

// ---------------------------------------------------------------- enc_att = img @ W_enc^T + b_enc
// M=6272, N=512, K=2048. grid (98, 2), block 256. 8x8 register tile, 64x256 block tile.
__global__ void k_enc(const float* __restrict__ img, const int* __restrict__ sidx,
                      const float* __restrict__ Wenc, const float* __restrict__ benc,
                      float* __restrict__ enc_att) {
    __shared__ float sA[16][68];    // [k][m], 68 pad keeps 16B row alignment
    __shared__ float sW[16][260];   // [k][n], 260*4=1040B rows, 16B aligned
    __shared__ size_t sRB[64];
    int mb = blockIdx.x, c0 = blockIdx.y * 256;
    int tid = threadIdx.x;
    int tm = tid >> 5, tn = tid & 31;
    if (tid < 64) {
        int row = mb * 64 + tid;
        int b = row / PP, p = row % PP;
        sRB[tid] = ((size_t)sidx[b] * PP + p) * ENCD;
    }
    __syncthreads();
    float acc[8][8];
#pragma unroll
    for (int i = 0; i < 8; i++)
#pragma unroll
        for (int j = 0; j < 8; j++) acc[i][j] = 0.f;

    for (int kk = 0; kk < ENCD; kk += 16) {
        // stage A: 64 m x 16 k  (transposed into [k][m])
        {
            int m = tid >> 2, kq = tid & 3;
            float4 v = *(const float4*)(img + sRB[m] + kk + kq * 4);
            sA[kq * 4 + 0][m] = v.x; sA[kq * 4 + 1][m] = v.y;
            sA[kq * 4 + 2][m] = v.z; sA[kq * 4 + 3][m] = v.w;
        }
        // stage B: 256 n x 16 k
        {
            int col = c0 + tid;
            const float* wr = Wenc + (size_t)col * ENCD + kk;
#pragma unroll
            for (int j = 0; j < 4; j++) {
                float4 v = *(const float4*)(wr + j * 4);
                sW[j * 4 + 0][tid] = v.x; sW[j * 4 + 1][tid] = v.y;
                sW[j * 4 + 2][tid] = v.z; sW[j * 4 + 3][tid] = v.w;
            }
        }
        __syncthreads();
#pragma unroll
        for (int k = 0; k < 16; k++) {
            float4 a0 = *(const float4*)&sA[k][tm * 8];
            float4 a1 = *(const float4*)&sA[k][tm * 8 + 4];
            float4 w0 = *(const float4*)&sW[k][tn * 4];
            float4 w1 = *(const float4*)&sW[k][128 + tn * 4];
            float av[8] = {a0.x, a0.y, a0.z, a0.w, a1.x, a1.y, a1.z, a1.w};
            float wv[8] = {w0.x, w0.y, w0.z, w0.w, w1.x, w1.y, w1.z, w1.w};
#pragma unroll
            for (int i = 0; i < 8; i++)
#pragma unroll
                for (int j = 0; j < 8; j++) acc[i][j] += av[i] * wv[j];
        }
        __syncthreads();
    }
    // epilogue
#pragma unroll
    for (int i = 0; i < 8; i++) {
        int row = mb * 64 + tm * 8 + i;
        float* orow = enc_att + (size_t)row * ATTD + c0;
        int ca = tn * 4, cb = 128 + tn * 4;
        float4 oa = {acc[i][0] + benc[c0 + ca + 0], acc[i][1] + benc[c0 + ca + 1],
                     acc[i][2] + benc[c0 + ca + 2], acc[i][3] + benc[c0 + ca + 3]};
        float4 ob = {acc[i][4] + benc[c0 + cb + 0], acc[i][5] + benc[c0 + cb + 1],
                     acc[i][6] + benc[c0 + cb + 2], acc[i][7] + benc[c0 + cb + 3]};
        *(float4*)(orow + ca) = oa;
        *(float4*)(orow + cb) = ob;
    }
}

// ---------------------------------------------------------------- g_base = emb_t @ W_ih[:, :512]^T + b_ih + b_hh
__global__ void k_gemb(const float* __restrict__ emb, const int* __restrict__ toks,
                       const int* __restrict__ sidx, const float* __restrict__ Wih,
                       const float* __restrict__ bih, const float* __restrict__ bhh,
                       float* __restrict__ gbase) {
    __shared__ float As[32][33];
    __shared__ float Ws[32][65];
    __shared__ size_t rb[32];
    int row0 = blockIdx.x * 32, col0 = blockIdx.y * 64;
    int tid = threadIdx.x;
    int tr = tid & 31, tc = tid >> 5;
    if (tid < 32) {
        int t = blockIdx.x, b = tid;
        int tok = toks[sidx[b] * LLEN + t];
        rb[tid] = (size_t)tok * EMBD;
    }
    __syncthreads();
    float acc[8] = {0, 0, 0, 0, 0, 0, 0, 0};
    for (int kk = 0; kk < EMBD; kk += 32) {
        for (int i = tid; i < 1024; i += 256) {
            int r = i >> 5, k = i & 31;
            As[r][k] = emb[rb[r] + kk + k];
        }
        for (int i = tid; i < 2048; i += 256) {
            int cc = i >> 5, k = i & 31;
            Ws[k][cc] = Wih[(size_t)(col0 + cc) * (EMBD + ENCD) + kk + k];
        }
        __syncthreads();
        for (int k = 0; k < 32; k++) {
            float a = As[tr][k];
#pragma unroll
            for (int j = 0; j < 8; j++) acc[j] += a * Ws[k][tc * 8 + j];
        }
        __syncthreads();
    }
    int row = row0 + tr;
    float* crow = gbase + (size_t)row * 2048 + col0 + tc * 8;
#pragma unroll
    for (int j = 0; j < 8; j++) {
        int col = col0 + tc * 8 + j;
        crow[j] = acc[j] + bih[col] + bhh[col];
    }
}

// ---------------------------------------------------------------- per-step: h projection (dec_att + beta gate, partials)
// C[col=2560][b=32] partial over k; grid (10 colchunk, 4 bgrp, 2 kc), block 256.
__global__ void k_hproj(const float* __restrict__ xT, const float* __restrict__ WhT,
                        float* __restrict__ hp) {
    int col = blockIdx.x * 256 + threadIdx.x;
    int bg = blockIdx.y;
    int k0 = blockIdx.z * 256;
    const float* Wp = WhT + (size_t)k0 * 2560 + col;
    const float* Xp = xT + 2048 * BB + k0 * BB + bg * 8;
    float acc[8] = {0, 0, 0, 0, 0, 0, 0, 0};
    for (int k = 0; k < 256; k++) {
        float w = Wp[(size_t)k * 2560];
        const float* x = Xp + k * BB;
#pragma unroll
        for (int j = 0; j < 8; j++) acc[j] += w * x[j];
    }
    float* gp = hp + ((size_t)(blockIdx.z * 2560 + col)) * BB + bg * 8;
    *(float4*)gp = make_float4(acc[0], acc[1], acc[2], acc[3]);
    *(float4*)(gp + 4) = make_float4(acc[4], acc[5], acc[6], acc[7]);
}

// ---------------------------------------------------------------- per-step: scores + softmax + alpha
__global__ void k_score(int t, const float* __restrict__ hp, const float* __restrict__ bdec,
                        const float* __restrict__ wfull, const float* __restrict__ enc_att,
                        const int* __restrict__ dlen, float* __restrict__ alpha_ws,
                        float* __restrict__ out_alpha) {
    int b = blockIdx.x, tid = threadIdx.x;
    __shared__ float sdec[512], swf[512], sal[256], sred[256];
    for (int a = tid; a < 512; a += 256) {
        sdec[a] = hp[(size_t)a * BB + b] + hp[(size_t)(2560 + a) * BB + b] + bdec[a];
        swf[a] = wfull[a];
    }
    __syncthreads();
    int wv = tid >> 6, ln = tid & 63;
    const float* eb = enc_att + (size_t)b * PP * ATTD;
    for (int p = wv; p < PP; p += 4) {
        const float* er = eb + (size_t)p * ATTD;
        float acc = 0.f;
        for (int a = ln; a < ATTD; a += 64) {
            float v = er[a] + sdec[a];
            acc += fmaxf(v, 0.f) * swf[a];
        }
        for (int off = 32; off; off >>= 1) acc += __shfl_down(acc, off);
        if (ln == 0) sal[p] = acc;
    }
    __syncthreads();
    float v = (tid < PP) ? sal[tid] : -1e30f;
    sred[tid] = v;
    __syncthreads();
    for (int s = 128; s; s >>= 1) { if (tid < s) sred[tid] = fmaxf(sred[tid], sred[tid + s]); __syncthreads(); }
    float mx = sred[0];
    __syncthreads();
    float e = (tid < PP) ? __expf(v - mx) : 0.f;
    sred[tid] = e;
    __syncthreads();
    for (int s = 128; s; s >>= 1) { if (tid < s) sred[tid] += sred[tid + s]; __syncthreads(); }
    float inv = 1.f / sred[0];
    bool active = t < dlen[b];
    if (tid < PP) {
        float al = e * inv;
        alpha_ws[b * 200 + tid] = al;
        out_alpha[((size_t)b * TT + t) * PP + tid] = active ? al : 0.f;
    }
}

// ---------------------------------------------------------------- per-step: awe = alpha@img, gated, -> xT (transposed)
__global__ void k_awe(const float* __restrict__ img, const int* __restrict__ sidx,
                      const float* __restrict__ alpha_ws, const float* __restrict__ hp,
                      const float* __restrict__ bbeta, float* __restrict__ xT) {
    int b = blockIdx.x, ec = blockIdx.y, tid = threadIdx.x;
    int e = ec * 256 + tid;
    __shared__ float sal[200];
    __shared__ int ssb;
    if (tid < PP) sal[tid] = alpha_ws[b * 200 + tid];
    if (tid == 0) ssb = sidx[b];
    __syncthreads();
    const float* ib = img + (size_t)ssb * PP * ENCD + e;
    float acc = 0.f;
    for (int p = 0; p < PP; p++) acc += sal[p] * ib[(size_t)p * ENCD];
    float graw = hp[(size_t)(512 + e) * BB + b] + hp[(size_t)(2560 + 512 + e) * BB + b] + bbeta[e];
    xT[e * BB + b] = acc * sigmf(graw);
}

// ---------------------------------------------------------------- per-step: gate-GEMM partials
// C[d=2048][b=32] = sum_k WgT[k][d]*xT[k][b]; grid (8 dgrp, 4 bgrp, 8 kc), block 256.
__global__ void k_gstep(const float* __restrict__ xT, const float* __restrict__ WgT,
                        float* __restrict__ gpart) {
    int d = blockIdx.x * 256 + threadIdx.x;
    int bg = blockIdx.y;
    int k0 = blockIdx.z * 320;
    const float* Wp = WgT + (size_t)k0 * 2048 + d;
    const float* Xp = xT + k0 * BB + bg * 8;
    float acc[8] = {0, 0, 0, 0, 0, 0, 0, 0};
    for (int k = 0; k < 320; k++) {
        float w = Wp[(size_t)k * 2048];
        const float* x = Xp + k * BB;
#pragma unroll
        for (int j = 0; j < 8; j++) acc[j] += w * x[j];
    }
    float* gp = gpart + ((size_t)(blockIdx.z * 2048 + d)) * BB + bg * 8;
    *(float4*)gp = make_float4(acc[0], acc[1], acc[2], acc[3]);
    *(float4*)(gp + 4) = make_float4(acc[4], acc[5], acc[6], acc[7]);
}

// ---------------------------------------------------------------- per-step: LSTM cell update
__global__ void k_update(int t, const float* __restrict__ gbase, const float* __restrict__ gpart,
                         const int* __restrict__ dlen, float* __restrict__ xT,
                         float* __restrict__ c, unsigned short* __restrict__ hB) {
    int b = blockIdx.x >> 1;
    int d = (blockIdx.x & 1) * 256 + threadIdx.x;
    bool active = t < dlen[b];
    const float* gb = gbase + ((size_t)t * BB + b) * 2048;
    float gi = gb[d], gf = gb[d + 512], gg = gb[d + 1024], go = gb[d + 1536];
#pragma unroll
    for (int kc = 0; kc < GKC; kc++) {
        const float* gp = gpart + ((size_t)kc * 2048) * BB + b;
        gi += gp[(size_t)d * BB];
        gf += gp[(size_t)(512 + d) * BB];
        gg += gp[(size_t)(1024 + d) * BB];
        go += gp[(size_t)(1536 + d) * BB];
    }
    float i_ = sigmf(gi), f_ = sigmf(gf), g_ = tanhf(gg), o_ = sigmf(go);
    float cv = c[b * DECD + d];
    float cn = f_ * cv + i_ * g_;
    float hn = o_ * tanhf(cn);
    float hv;
    if (active) { c[b * DECD + d] = cn; xT[(2048 + d) * BB + b] = hn; hv = hn; }
    else hv = xT[(2048 + d) * BB + b];
    hB[((size_t)t * BB + b) * DECD + d] = f2bf(hv);
}

// ---------------------------------------------------------------- predictions via bf16 MFMA
// C[m=1632][n=10000] = hB @ WfcB^T; grid (51 t, 40 nb), block 256 (4 waves).
// Block tile 32(m) x 256(n); wave tile 32x64; 2x4 mfma_f32_16x16x32_bf16 frags.
__global__ void k_pred(const unsigned short* __restrict__ hB, const unsigned short* __restrict__ WfcB,
                       const float* __restrict__ bfc, const int* __restrict__ dlen,
                       float* __restrict__ out) {
    __shared__ unsigned short sA[32 * 40];   // [m][k], row stride 40 shorts (80B)
    __shared__ unsigned short sB[256 * 40];  // [n][k]
    int t = blockIdx.x, n0 = blockIdx.y * 256;
    int tid = threadIdx.x;
    int wv = tid >> 6, lane = tid & 63;
    int quad = lane >> 4, l16 = lane & 15;

    floatx4 acc[2][4];
#pragma unroll
    for (int i = 0; i < 2; i++)
#pragma unroll
        for (int j = 0; j < 4; j++) acc[i][j] = (floatx4){0.f, 0.f, 0.f, 0.f};

    for (int kk = 0; kk < 512; kk += 32) {
        // stage A: 32 m x 32 k (bf16) = 512 uints
        {
            unsigned int* dst = (unsigned int*)sA;
            for (int j = 0; j < 2; j++) {
                int idx = tid + j * 256;
                int m = idx >> 4, kp = idx & 15;
                dst[m * 20 + kp] = ((const unsigned int*)(hB + ((size_t)(t * 32 + m)) * 512 + kk))[kp];
            }
        }
        // stage B: 256 n x 32 k = 4096 uints
        {
            unsigned int* dst = (unsigned int*)sB;
#pragma unroll
            for (int j = 0; j < 16; j++) {
                int idx = tid + j * 256;
                int n = idx >> 4, kp = idx & 15;
                int gn = n0 + n;
                unsigned int v = 0u;
                if (gn < VV) v = ((const unsigned int*)(WfcB + (size_t)gn * 512 + kk))[kp];
                dst[n * 20 + kp] = v;
            }
        }
        __syncthreads();
        short8 af[2], bf[4];
#pragma unroll
        for (int mt = 0; mt < 2; mt++)
            af[mt] = *(const short8*)(sA + (mt * 16 + l16) * 40 + quad * 8);
#pragma unroll
        for (int nt = 0; nt < 4; nt++) {
            int nl = wv * 64 + nt * 16 + l16;
            bf[nt] = *(const short8*)(sB + nl * 40 + quad * 8);
        }
#pragma unroll
        for (int mt = 0; mt < 2; mt++)
#pragma unroll
            for (int nt = 0; nt < 4; nt++)
                acc[mt][nt] = __builtin_amdgcn_mfma_f32_16x16x32_bf16(af[mt], bf[nt], acc[mt][nt], 0, 0, 0);
        __syncthreads();
    }
    // epilogue: C/D layout col=lane&15 (n), row=quad*4+reg (m)
#pragma unroll
    for (int mt = 0; mt < 2; mt++) {
#pragma unroll
        for (int r = 0; r < 4; r++) {
            int m = mt * 16 + quad * 4 + r;   // = b
            bool active = t < dlen[m];
            float* orow = out + OFF_PRED + ((size_t)m * TT + t) * VV;
#pragma unroll
            for (int nt = 0; nt < 4; nt++) {
                int n = n0 + wv * 64 + nt * 16 + l16;
                if (n < VV) orow[n] = active ? (acc[mt][nt][r] + bfc[n]) : 0.f;
            }
        }
    }
}

// ---------------------------------------------------------------- launch
extern "C" void kernel_launch(void* const* d_in, const int* in_sizes, int n_in,
                              void* d_out, int out_size, void* d_ws, size_t ws_size,
                              hipStream_t stream) {
    const float* img   = (const float*)d_in[0];
    const int*   toks  = (const int*)d_in[1];
    const int*   lens  = (const int*)d_in[2];
    const float* Wenc  = (const float*)d_in[3];
    const float* benc  = (const float*)d_in[4];
    const float* Wdec  = (const float*)d_in[5];
    const float* bdec  = (const float*)d_in[6];
    const float* wfull = (const float*)d_in[7];
    // d_in[8] = b_full (scalar 0; softmax-invariant)
    const float* emb   = (const float*)d_in[9];
    const float* Wih   = (const float*)d_in[10];
    const float* bih   = (const float*)d_in[11];
    const float* Whh   = (const float*)d_in[12];
    const float* bhh   = (const float*)d_in[13];
    const float* Wh0   = (const float*)d_in[14];
    const float* bh0   = (const float*)d_in[15];
    const float* Wc0   = (const float*)d_in[16];
    const float* bc0   = (const float*)d_in[17];
    const float* Wbeta = (const float*)d_in[18];
    const float* bbeta = (const float*)d_in[19];
    const float* Wfc   = (const float*)d_in[20];
    const float* bfc   = (const float*)d_in[21];
    float* out = (float*)d_out;

    // workspace layout
    char* ws = (char*)d_ws;
    int* sidx = (int*)ws;                  ws += 256;
    int* dlen = (int*)ws;                  ws += 256;
    float* c        = (float*)ws;          ws += (size_t)BB * DECD * 4;          // 64 KB
    float* xT       = (float*)ws;          ws += (size_t)2560 * BB * 4;          // 320 KB  [k][b]; tail = hT
    float* hp       = (float*)ws;          ws += (size_t)2 * 2560 * BB * 4;      // 640 KB  hproj partials
    float* alpha_ws = (float*)ws;          ws += (size_t)BB * 200 * 4;           // 25 KB
    float* gpart    = (float*)ws;          ws += (size_t)GKC * 2048 * BB * 4;    // 2 MB
    unsigned short* hB = (unsigned short*)ws; ws += (size_t)TT * BB * DECD * 2;  // 1.7 MB
    float* WgT      = (float*)ws;          ws += (size_t)2560 * 2048 * 4;        // 21 MB
    float* WhT      = (float*)ws;          ws += (size_t)512 * 2560 * 4;         // 5.2 MB
    unsigned int* WfcB = (unsigned int*)ws; ws += (size_t)VV * 512 * 2;          // 10.2 MB
    float* enc_att  = (float*)ws;          ws += (size_t)BB * PP * ATTD * 4;     // 12.8 MB
    float* gbase    = (float*)ws;          ws += (size_t)TT * BB * 2048 * 4;     // 13.4 MB

    k_sort<<<1, 64, 0, stream>>>(toks, lens, sidx, dlen, out);
    k_init<<<32, 256, 0, stream>>>(img, sidx, Wh0, bh0, Wc0, bc0, xT, c);
    k_twg<<<dim3(80, 64), 256, 0, stream>>>(Wih, Whh, WgT);
    k_twh<<<dim3(16, 80), 256, 0, stream>>>(Wdec, Wbeta, WhT);
    k_cvtfc<<<2500, 256, 0, stream>>>(Wfc, WfcB);
    k_enc<<<dim3(98, 2), 256, 0, stream>>>(img, sidx, Wenc, benc, enc_att);
    k_gemb<<<dim3(51, 32), 256, 0, stream>>>(emb, toks, sidx, Wih, bih, bhh, gbase);

    for (int t = 0; t < TT; t++) {
        k_hproj<<<dim3(10, 4, 2), 256, 0, stream>>>(xT, WhT, hp);
        k_score<<<32, 256, 0, stream>>>(t, hp, bdec, wfull, enc_att, dlen,
                                        alpha_ws, out + OFF_ALPHA);
        k_awe<<<dim3(32, 8), 256, 0, stream>>>(img, sidx, alpha_ws, hp, bbeta, xT);
        k_gstep<<<dim3(8, 4, GKC), 256, 0, stream>>>(xT, WgT, gpart);
        k_update<<<64, 256, 0, stream>>>(t, gbase, gpart, dlen, xT, c, hB);
    }

    k_pred<<<dim3(TT, 40), 256, 0, stream>>>(hB, (const unsigned short*)WfcB, bfc, dlen, out);
}